// Round 4
// baseline (61.727 us; speedup 1.0000x reference)
//
#include <hip/hip_runtime.h>
#include <hip/hip_cooperative_groups.h>

namespace cg = cooperative_groups;

#define NS 8192          // 4*2048 samples
#define D 14
#define CS 16384         // 2^14 codes
#define NB 128           // blocks (1 wave each)
#define BT 64
#define EPS 1e-5f
#define LNEPS (-11.512925464970229f) // ln(1e-5)
#define THRESH 30.0f     // drop codes with logit-gap > 30 (p < 9e-14)

__device__ __forceinline__ float waveRedSum(float v) {
    #pragma unroll
    for (int off = 32; off; off >>= 1) v += __shfl_xor(v, off);
    return v;
}

// ---------------------------------------------------------------------------
// Single cooperative kernel, 128 blocks x 64 threads (1 wave/block), 1 sample
// per thread.
//  phase 0: zero hist (atomicExch -> lands at device-coherent point),
//           h = x@Win^T+bin, q=sign(h), out = q@Wout^T+bout, idx bits,
//           commit partial (wave shfl reduce), soft-dim compaction to LDS.
//  grid.sync()
//  phase 1: Gray-code enumeration of the 2^S codes with 2|a_d| < THRESH
//           (all other codes have p < 9e-14; total contribution < 2e-8 vs
//           threshold ~1.5e-2). atomicAdd into hist; per-sample-entropy
//           partial sum p*max(t, ln eps)  (== -p*log(clip(p,eps))).
//  grid.sync()
//  phase 2: block 0 only: codebook entropy from hist (256 bins/lane via
//           float4) + fold entPart/commitPart -> aux scalar.
// ---------------------------------------------------------------------------
__global__ __launch_bounds__(BT) void lfq_all(
    const float* __restrict__ x, const float* __restrict__ Win,
    const float* __restrict__ bin, const float* __restrict__ Wout,
    const float* __restrict__ bout,
    float* __restrict__ out, float* __restrict__ idxOut,
    float* __restrict__ hist, float* __restrict__ entPart,
    float* __restrict__ commitPart, float* __restrict__ aux)
{
    cg::grid_group grid = cg::this_grid();
    const int tid = threadIdx.x;
    const int b = blockIdx.x;
    const int i = b * BT + tid;

    // ---- phase 0a: zero my 2 histogram bins at the coherent point ----
    atomicExch(&hist[2 * i], 0.f);
    atomicExch(&hist[2 * i + 1], 0.f);

    // ---- phase 0b: per-sample projection / quantization ----
    float xv[D];
    #pragma unroll
    for (int k = 0; k < D; k++) xv[k] = x[i * D + k];

    float h[D];
    #pragma unroll
    for (int d = 0; d < D; d++) {
        float s = bin[d];
        #pragma unroll
        for (int k = 0; k < D; k++) s = fmaf(xv[k], Win[d * D + k], s);
        h[d] = s;
    }

    float q[D];
    int idx = 0;
    float commit = 0.f;
    #pragma unroll
    for (int d = 0; d < D; d++) {
        const bool pos = h[d] > 0.f;
        q[d] = pos ? 1.f : -1.f;
        idx |= (pos ? 1 : 0) << (13 - d);
        const float e = h[d] - q[d];
        commit = fmaf(e, e, commit);
    }

    #pragma unroll
    for (int e = 0; e < D; e++) {
        float s = bout[e];
        #pragma unroll
        for (int d = 0; d < D; d++) s = fmaf(q[d], Wout[e * D + d], s);
        out[i * D + e] = s;
    }
    idxOut[i] = (float)idx;

    // soft-dim compaction; t0 = -sum_d log1p(exp(-2|a_d|)),  a_d = 200 h_d.
    // LDS layout [k][tid]: dynamic index k keeps bank = tid%32, conflict-free,
    // and keeps the runtime-indexed array out of VGPRs (no scratch spill).
    __shared__ float sA[D * BT];
    __shared__ int   sB[D * BT];
    int S = 0;
    float t0 = 0.f;
    #pragma unroll
    for (int d = 0; d < D; d++) {
        const float ab = fabsf(200.0f * h[d]);
        t0 -= __logf(1.0f + __expf(-2.f * ab));
        const float twoA = 2.f * ab;
        if (twoA < THRESH) {
            sA[S * BT + tid] = twoA;
            sB[S * BT + tid] = 1 << (13 - d);
            S++;
        }
    }

    const float cm = waveRedSum(commit);
    if (tid == 0) atomicExch(&commitPart[b], cm);

    grid.sync();   // hist fully zeroed everywhere

    // ---- phase 1: Gray-code enumeration + hist atomics + entropy ----
    float ent;
    {
        const float p0 = __expf(t0);
        ent = p0 * fmaxf(t0, LNEPS);
        atomicAdd(&hist[idx], p0);
    }
    float tcur = t0;
    int jj = idx;
    const int total = 1 << S;
    for (int m = 1; m < total; m++) {
        const int k = __ffs(m) - 1;          // toggled Gray bit
        const int gn = m ^ (m >> 1);
        const float tw = sA[k * BT + tid];
        const int bm = sB[k * BT + tid];
        tcur += ((gn >> k) & 1) ? -tw : tw;
        jj ^= bm;
        const float p = __expf(tcur);
        ent = fmaf(p, fmaxf(tcur, LNEPS), ent);
        atomicAdd(&hist[jj], p);
    }

    const float es = waveRedSum(ent);
    if (tid == 0) atomicExch(&entPart[b], es);

    grid.sync();   // all atomics + partials visible

    // ---- phase 2: block 0 folds everything into aux ----
    if (b == 0) {
        float cb = 0.f;
        const float4* h4 = (const float4*)hist;
        // 16384 bins / 64 lanes = 256 bins = 64 float4 per lane, coalesced
        for (int u = 0; u < 64; u++) {
            const float4 v = h4[u * BT + tid];
            #pragma unroll
            for (int w = 0; w < 4; w++) {
                const float qv = (&v.x)[w] * (1.0f / NS);
                cb += qv * __logf(fmaxf(qv, EPS));
            }
        }
        float es2 = entPart[tid] + entPart[tid + 64];
        float cm2 = commitPart[tid] + commitPart[tid + 64];
        cb  = waveRedSum(cb);
        es2 = waveRedSum(es2);
        cm2 = waveRedSum(cm2);
        if (tid == 0) {
            const float codebook_entropy = -cb;
            const float per_sample_entropy = -es2 / (float)NS;
            const float commit_loss = cm2 / (float)(NS * D);
            const float entropy_aux = per_sample_entropy - 1.0f * codebook_entropy;
            aux[0] = entropy_aux * 0.1f + commit_loss * 0.25f;
        }
    }
}

extern "C" void kernel_launch(void* const* d_in, const int* in_sizes, int n_in,
                              void* d_out, int out_size, void* d_ws, size_t ws_size,
                              hipStream_t stream) {
    const float* x    = (const float*)d_in[0];
    const float* Win  = (const float*)d_in[1];
    const float* bin  = (const float*)d_in[2];
    const float* Wout = (const float*)d_in[3];
    const float* bout = (const float*)d_in[4];

    float* out    = (float*)d_out;            // [NS][D]
    float* idxOut = out + (size_t)NS * D;     // [NS] indices as float
    float* aux    = idxOut + NS;              // scalar

    float* ws         = (float*)d_ws;
    float* hist       = ws;                   // CS floats (64 KB)
    float* entPart    = hist + CS;            // 128 floats
    float* commitPart = entPart + NB;         // 128 floats

    void* args[] = {
        (void*)&x, (void*)&Win, (void*)&bin, (void*)&Wout, (void*)&bout,
        (void*)&out, (void*)&idxOut, (void*)&hist, (void*)&entPart,
        (void*)&commitPart, (void*)&aux
    };
    hipLaunchCooperativeKernel((const void*)lfq_all, dim3(NB), dim3(BT),
                               args, 0, stream);
}

// Round 5
// 30.936 us; speedup vs baseline: 1.9953x; 1.9953x over previous
//
#include <hip/hip_runtime.h>

#define NS 8192          // 4*2048 samples
#define D 14
#define CS 16384         // 2^14 codes
#define NB 128           // k1 blocks, 1 wave each
#define BT 64
#define FB 64            // k2 blocks
#define EPS 1e-5f
#define LNEPS (-11.512925464970229f) // ln(1e-5)
#define THRESH 30.0f     // drop codes with logit-gap > 30 (p < 9e-14)

__device__ __forceinline__ float waveRedSum(float v) {
    #pragma unroll
    for (int off = 32; off; off >>= 1) v += __shfl_xor(v, off);
    return v;
}

// ---------------------------------------------------------------------------
// k1: one wave per block, one sample per lane. Per-block LDS histogram
// (64 KB, gfx950 has 160 KB) removes the need for a pre-zeroed global hist:
//  - zero own LDS hist
//  - h = x@Win^T+bin ; q = sign(h) ; out = q@Wout^T+bout ; idx bits ; commit
//  - soft-dim compaction (2|a_d| < THRESH; all dropped codes have p < 9e-14,
//    total contribution < 2e-8 vs aux threshold ~1e-2)
//  - Gray-code enumeration of 2^S near-max codes: LDS atomicAdd into hist,
//    per-sample entropy partial sum p*max(t,ln eps) == -p*log(clip(p,eps))
//  - dump LDS hist to blockHist[b] (coalesced float4), wave-reduce ent/commit
//  - block 0 lane 0 zeroes auxAcc + counter for k2 (stream order makes this
//    safe: k1 completes before k2 starts)
// ---------------------------------------------------------------------------
__global__ __launch_bounds__(BT) void lfq_main(
    const float* __restrict__ x, const float* __restrict__ Win,
    const float* __restrict__ bin, const float* __restrict__ Wout,
    const float* __restrict__ bout,
    float* __restrict__ out, float* __restrict__ idxOut,
    float* __restrict__ blockHist, float* __restrict__ entPart,
    float* __restrict__ commitPart, float* __restrict__ auxAcc,
    int* __restrict__ counter)
{
    __shared__ float shist[CS];    // 64 KB
    __shared__ float sA[D * BT];   // soft-dim 2|a|, [k][lane] -> bank = lane%32
    __shared__ int   sB[D * BT];   // soft-dim xor mask, [k][lane]

    const int tid = threadIdx.x;
    const int b = blockIdx.x;
    const int i = b * BT + tid;

    // zero LDS hist: 64 float4 per lane
    float4* sh4 = (float4*)shist;
    #pragma unroll
    for (int u = 0; u < CS / 4 / BT; u++)
        sh4[u * BT + tid] = make_float4(0.f, 0.f, 0.f, 0.f);

    if (b == 0 && tid == 0) { auxAcc[0] = 0.f; counter[0] = 0; }

    // ---- per-sample projection / quantization ----
    float xv[D];
    #pragma unroll
    for (int k = 0; k < D; k++) xv[k] = x[i * D + k];

    float h[D];
    #pragma unroll
    for (int d = 0; d < D; d++) {
        float s = bin[d];
        #pragma unroll
        for (int k = 0; k < D; k++) s = fmaf(xv[k], Win[d * D + k], s);
        h[d] = s;
    }

    float q[D];
    int idx = 0;
    float commit = 0.f;
    #pragma unroll
    for (int d = 0; d < D; d++) {
        const bool pos = h[d] > 0.f;
        q[d] = pos ? 1.f : -1.f;
        idx |= (pos ? 1 : 0) << (13 - d);
        const float e = h[d] - q[d];
        commit = fmaf(e, e, commit);
    }

    #pragma unroll
    for (int e = 0; e < D; e++) {
        float s = bout[e];
        #pragma unroll
        for (int d = 0; d < D; d++) s = fmaf(q[d], Wout[e * D + d], s);
        out[i * D + e] = s;
    }
    idxOut[i] = (float)idx;

    // soft-dim compaction; t0 = -sum_d log1p(exp(-2|a_d|)), a_d = 200 h_d
    int S = 0;
    float t0 = 0.f;
    #pragma unroll
    for (int d = 0; d < D; d++) {
        const float ab = fabsf(200.0f * h[d]);
        t0 -= __logf(1.0f + __expf(-2.f * ab));
        const float twoA = 2.f * ab;
        if (twoA < THRESH) {
            sA[S * BT + tid] = twoA;
            sB[S * BT + tid] = 1 << (13 - d);
            S++;
        }
    }

    __syncthreads();   // hist zeroing complete (lists are lane-private)

    // ---- Gray-code enumeration, LDS atomics ----
    float ent;
    {
        const float p0 = __expf(t0);
        ent = p0 * fmaxf(t0, LNEPS);
        atomicAdd(&shist[idx], p0);
    }
    float tcur = t0;
    int jj = idx;
    const int total = 1 << S;
    for (int m = 1; m < total; m++) {
        const int k = __ffs(m) - 1;          // toggled Gray bit
        const int gn = m ^ (m >> 1);
        const float tw = sA[k * BT + tid];
        const int bm = sB[k * BT + tid];
        tcur += ((gn >> k) & 1) ? -tw : tw;
        jj ^= bm;
        const float p = __expf(tcur);
        ent = fmaf(p, fmaxf(tcur, LNEPS), ent);
        atomicAdd(&shist[jj], p);
    }

    const float es = waveRedSum(ent);
    const float cm = waveRedSum(commit);
    if (tid == 0) { entPart[b] = es; commitPart[b] = cm; }

    __syncthreads();   // all LDS atomics complete

    // dump block histogram (coalesced float4)
    float4* bh4 = (float4*)(blockHist + (size_t)b * CS);
    #pragma unroll
    for (int u = 0; u < CS / 4 / BT; u++)
        bh4[u * BT + tid] = sh4[u * BT + tid];
}

// ---------------------------------------------------------------------------
// k2: fold 128 block-histograms -> codebook entropy; last-arriving block
// (atomic counter) folds ent/commit partials and writes the aux scalar.
// 64 blocks x 256 threads, one bin per thread.
// ---------------------------------------------------------------------------
__global__ __launch_bounds__(256) void lfq_fold(
    const float* __restrict__ blockHist, const float* __restrict__ entPart,
    const float* __restrict__ commitPart, float* __restrict__ auxAcc,
    int* __restrict__ counter, float* __restrict__ aux)
{
    const int t = threadIdx.x;
    const int j = blockIdx.x * 256 + t;

    float s = 0.f;
    #pragma unroll 8
    for (int bb = 0; bb < NB; bb++) s += blockHist[(size_t)bb * CS + j];
    const float qv = s * (1.0f / NS);
    float cb = qv * __logf(fmaxf(qv, EPS));

    __shared__ float r[256];
    r[t] = cb;
    __syncthreads();
    #pragma unroll
    for (int st = 128; st > 0; st >>= 1) {
        if (t < st) r[t] += r[t + st];
        __syncthreads();
    }

    __shared__ int done;
    if (t == 0) {
        atomicAdd(auxAcc, r[0]);
        __threadfence();
        const int old = atomicAdd(counter, 1);
        done = (old == FB - 1) ? 1 : 0;
    }
    __syncthreads();

    if (done) {
        float es = (t < NB) ? entPart[t] : 0.f;
        float cm = (t < NB) ? commitPart[t] : 0.f;
        __shared__ float r2[256], r3[256];
        r2[t] = es; r3[t] = cm;
        __syncthreads();
        #pragma unroll
        for (int st = 128; st > 0; st >>= 1) {
            if (t < st) { r2[t] += r2[t + st]; r3[t] += r3[t + st]; }
            __syncthreads();
        }
        if (t == 0) {
            __threadfence();
            const float cbAll = atomicAdd(auxAcc, 0.0f);  // coherent read
            const float codebook_entropy = -cbAll;
            const float per_sample_entropy = -r2[0] / (float)NS;
            const float commit_loss = r3[0] / (float)(NS * D);
            const float entropy_aux = per_sample_entropy - codebook_entropy;
            aux[0] = entropy_aux * 0.1f + commit_loss * 0.25f;
        }
    }
}

extern "C" void kernel_launch(void* const* d_in, const int* in_sizes, int n_in,
                              void* d_out, int out_size, void* d_ws, size_t ws_size,
                              hipStream_t stream) {
    const float* x    = (const float*)d_in[0];
    const float* Win  = (const float*)d_in[1];
    const float* bin  = (const float*)d_in[2];
    const float* Wout = (const float*)d_in[3];
    const float* bout = (const float*)d_in[4];

    float* out    = (float*)d_out;            // [NS][D]
    float* idxOut = out + (size_t)NS * D;     // [NS] indices as float
    float* aux    = idxOut + NS;              // scalar

    float* ws         = (float*)d_ws;
    float* blockHist  = ws;                        // NB*CS floats (8 MB)
    float* entPart    = blockHist + (size_t)NB * CS; // 128
    float* commitPart = entPart + NB;              // 128
    float* auxAcc     = commitPart + NB;           // 1
    int*   counter    = (int*)(auxAcc + 1);        // 1

    lfq_main<<<NB, BT, 0, stream>>>(x, Win, bin, Wout, bout,
                                    out, idxOut, blockHist, entPart,
                                    commitPart, auxAcc, counter);
    lfq_fold<<<FB, 256, 0, stream>>>(blockHist, entPart, commitPart,
                                     auxAcc, counter, aux);
}

// Round 6
// 27.240 us; speedup vs baseline: 2.2660x; 1.1357x over previous
//
#include <hip/hip_runtime.h>

#define NS 8192          // 4*2048 samples
#define D 14
#define CS 16384         // 2^14 codes
#define NB 128           // main blocks, 1 wave each
#define BT 64
#define FB 16            // fold blocks
#define EPS 1e-5f
#define LNEPS (-11.512925464970229f) // ln(1e-5)
#define THRESH 30.0f     // drop codes with logit-gap > 30 (p < 9e-14)

__device__ __forceinline__ float waveRedSum(float v) {
    #pragma unroll
    for (int off = 32; off; off >>= 1) v += __shfl_xor(v, off);
    return v;
}

// ---------------------------------------------------------------------------
// zero: 64 KB global hist + the two fold scalars. 16 blocks x 256 x float4.
// ---------------------------------------------------------------------------
__global__ __launch_bounds__(256) void lfq_zero(
    float* __restrict__ hist, float* __restrict__ auxAcc,
    int* __restrict__ counter)
{
    ((float4*)hist)[blockIdx.x * 256 + threadIdx.x] =
        make_float4(0.f, 0.f, 0.f, 0.f);
    if (blockIdx.x == 0 && threadIdx.x == 0) { auxAcc[0] = 0.f; counter[0] = 0; }
}

// ---------------------------------------------------------------------------
// main: one wave per block, one sample per lane.
//  - h = x@Win^T+bin ; q = sign(h) ; out = q@Wout^T+bout ; idx bits ; commit
//  - soft-dim compaction (2|a_d| < THRESH; dropped codes have p < 9e-14,
//    total contribution < 2e-8 vs aux threshold ~1e-2)
//  - Gray-code enumeration of the 2^S near-max codes: global atomicAdd into
//    the 64 KB hist (L2/L3-resident, ~33K adds total, low contention);
//    per-sample entropy partial sum p*max(t,ln eps) == -p*log(clip(p,eps))
//  - wave-reduce ent/commit -> plain per-block partial stores
// Soft lists in LDS laid out [k][lane] (bank = lane%32, conflict-free) to
// keep the runtime-indexed array out of VGPRs (rule #20: no scratch spill).
// ---------------------------------------------------------------------------
__global__ __launch_bounds__(BT) void lfq_main(
    const float* __restrict__ x, const float* __restrict__ Win,
    const float* __restrict__ bin, const float* __restrict__ Wout,
    const float* __restrict__ bout,
    float* __restrict__ out, float* __restrict__ idxOut,
    float* __restrict__ hist, float* __restrict__ entPart,
    float* __restrict__ commitPart)
{
    const int tid = threadIdx.x;
    const int b = blockIdx.x;
    const int i = b * BT + tid;

    float xv[D];
    #pragma unroll
    for (int k = 0; k < D; k++) xv[k] = x[i * D + k];

    float h[D];
    #pragma unroll
    for (int d = 0; d < D; d++) {
        float s = bin[d];
        #pragma unroll
        for (int k = 0; k < D; k++) s = fmaf(xv[k], Win[d * D + k], s);
        h[d] = s;
    }

    float q[D];
    int idx = 0;
    float commit = 0.f;
    #pragma unroll
    for (int d = 0; d < D; d++) {
        const bool pos = h[d] > 0.f;
        q[d] = pos ? 1.f : -1.f;
        idx |= (pos ? 1 : 0) << (13 - d);
        const float e = h[d] - q[d];
        commit = fmaf(e, e, commit);
    }

    #pragma unroll
    for (int e = 0; e < D; e++) {
        float s = bout[e];
        #pragma unroll
        for (int d = 0; d < D; d++) s = fmaf(q[d], Wout[e * D + d], s);
        out[i * D + e] = s;
    }
    idxOut[i] = (float)idx;

    // soft-dim compaction; t0 = -sum_d log1p(exp(-2|a_d|)), a_d = 200 h_d
    __shared__ float sA[D * BT];
    __shared__ int   sB[D * BT];
    int S = 0;
    float t0 = 0.f;
    #pragma unroll
    for (int d = 0; d < D; d++) {
        const float ab = fabsf(200.0f * h[d]);
        t0 -= __logf(1.0f + __expf(-2.f * ab));
        const float twoA = 2.f * ab;
        if (twoA < THRESH) {
            sA[S * BT + tid] = twoA;
            sB[S * BT + tid] = 1 << (13 - d);
            S++;
        }
    }

    // Gray-code enumeration of the 2^S near-max codes
    float ent;
    {
        const float p0 = __expf(t0);
        ent = p0 * fmaxf(t0, LNEPS);
        atomicAdd(&hist[idx], p0);
    }
    float tcur = t0;
    int jj = idx;
    const int total = 1 << S;
    for (int m = 1; m < total; m++) {
        const int k = __ffs(m) - 1;          // toggled Gray bit
        const int gn = m ^ (m >> 1);
        const float tw = sA[k * BT + tid];
        const int bm = sB[k * BT + tid];
        tcur += ((gn >> k) & 1) ? -tw : tw;
        jj ^= bm;
        const float p = __expf(tcur);
        ent = fmaf(p, fmaxf(tcur, LNEPS), ent);
        atomicAdd(&hist[jj], p);
    }

    const float es = waveRedSum(ent);
    const float cm = waveRedSum(commit);
    if (tid == 0) { entPart[b] = es; commitPart[b] = cm; }
}

// ---------------------------------------------------------------------------
// fold: 16 blocks x 256 threads, 4 bins (1 float4) per thread ->
// codebook-entropy partials; last-arriving block (counter) folds ent/commit
// partials and writes the aux scalar. Kernel boundary after lfq_main gives
// device-wide visibility of the hist atomics for plain loads here.
// ---------------------------------------------------------------------------
__global__ __launch_bounds__(256) void lfq_fold(
    const float* __restrict__ hist, const float* __restrict__ entPart,
    const float* __restrict__ commitPart, float* __restrict__ auxAcc,
    int* __restrict__ counter, float* __restrict__ aux)
{
    const int t = threadIdx.x;
    const float4 v = ((const float4*)hist)[blockIdx.x * 256 + t];
    float cb = 0.f;
    #pragma unroll
    for (int w = 0; w < 4; w++) {
        const float qv = (&v.x)[w] * (1.0f / NS);
        cb += qv * __logf(fmaxf(qv, EPS));
    }

    __shared__ float r[256];
    r[t] = cb;
    __syncthreads();
    #pragma unroll
    for (int st = 128; st > 0; st >>= 1) {
        if (t < st) r[t] += r[t + st];
        __syncthreads();
    }

    __shared__ int done;
    if (t == 0) {
        atomicAdd(auxAcc, r[0]);
        __threadfence();
        const int old = atomicAdd(counter, 1);
        done = (old == FB - 1) ? 1 : 0;
    }
    __syncthreads();

    if (done) {
        float es = (t < NB) ? entPart[t] : 0.f;
        float cm = (t < NB) ? commitPart[t] : 0.f;
        __shared__ float r2[256], r3[256];
        r2[t] = es; r3[t] = cm;
        __syncthreads();
        #pragma unroll
        for (int st = 128; st > 0; st >>= 1) {
            if (t < st) { r2[t] += r2[t + st]; r3[t] += r3[t + st]; }
            __syncthreads();
        }
        if (t == 0) {
            const float cbAll = atomicAdd(auxAcc, 0.0f);  // coherent read
            const float codebook_entropy = -cbAll;
            const float per_sample_entropy = -r2[0] / (float)NS;
            const float commit_loss = r3[0] / (float)(NS * D);
            const float entropy_aux = per_sample_entropy - codebook_entropy;
            aux[0] = entropy_aux * 0.1f + commit_loss * 0.25f;
        }
    }
}

extern "C" void kernel_launch(void* const* d_in, const int* in_sizes, int n_in,
                              void* d_out, int out_size, void* d_ws, size_t ws_size,
                              hipStream_t stream) {
    const float* x    = (const float*)d_in[0];
    const float* Win  = (const float*)d_in[1];
    const float* bin  = (const float*)d_in[2];
    const float* Wout = (const float*)d_in[3];
    const float* bout = (const float*)d_in[4];

    float* out    = (float*)d_out;            // [NS][D]
    float* idxOut = out + (size_t)NS * D;     // [NS] indices as float
    float* aux    = idxOut + NS;              // scalar

    float* ws         = (float*)d_ws;
    float* hist       = ws;                   // CS floats (64 KB)
    float* entPart    = hist + CS;            // 128
    float* commitPart = entPart + NB;         // 128
    float* auxAcc     = commitPart + NB;      // 1
    int*   counter    = (int*)(auxAcc + 1);   // 1

    lfq_zero<<<FB, 256, 0, stream>>>(hist, auxAcc, counter);
    lfq_main<<<NB, BT, 0, stream>>>(x, Win, bin, Wout, bout,
                                    out, idxOut, hist, entPart, commitPart);
    lfq_fold<<<FB, 256, 0, stream>>>(hist, entPart, commitPart,
                                     auxAcc, counter, aux);
}